// Round 5
// baseline (264.622 us; speedup 1.0000x reference)
//
#include <hip/hip_runtime.h>

#define N_NODES 100000
#define K_EIG   256
#define C_CH    128
#define BN      320              // rows per split-K chunk
#define NITER   5                // BN/64
#define NCHUNK  313              // ceil(N_NODES / BN); 313*320 = 100160
#define NTP     8                // kt(2) x ctile(4) output sub-tiles
#define PART_TILE (128*32)       // floats per partial tile; 8*313*16KB = 41.0 MB <= d_out 51.2MB
#define G2_BLOCKS 782            // ceil(N_NODES / 128)

typedef __attribute__((ext_vector_type(8))) short         short8;
typedef __attribute__((ext_vector_type(4))) float         float4v;
typedef __attribute__((ext_vector_type(2))) float         float2v;
typedef __attribute__((ext_vector_type(2))) unsigned int  uint2v;

// fp32 -> bf16 bits with round-to-nearest-even
__device__ __forceinline__ unsigned int bf16_bits(float f) {
  union { float f; unsigned int u; } v; v.f = f;
  unsigned int r = v.u + 0x7fffu + ((v.u >> 16) & 1u);
  return r >> 16;
}
__device__ __forceinline__ unsigned int pack2(float a, float b) {
  return bf16_bits(a) | (bf16_bits(b) << 16);
}

// XOR-swizzled dword index into a k-major LDS tile: row-stride 32 dw (64 bf16).
// Keeps b64 staging writes and b128 fragment reads <=2 lanes/bank (free).
__device__ __forceinline__ int swz(int row, int nd) {
  return row * 32 + (nd ^ (((row ^ (row >> 3)) & 7) << 2));
}

// ---------------------------------------------------------------------------
// GEMM1: split-K MFMA. Round-4 diagnosis: occupancy GRID-limited (1044 blocks
// = 4.08 avail/CU, measured 2.56 -> only ~2.5 waves/SIMD covering ~650cy of
// exposed HBM latency per iter). Fix: 8-way output split (tp = kt*4+ctile,
// tiles 128k x 32c) -> 2504 blocks (9.8 avail/CU), LDS 20KB (8 blocks/CU cap),
// prefetch regs 40, acc 16 (AGPRs). Extra ev/x re-reads are L3-absorbed
// (unique data 153MB << 256MB; tp-copies dispatch within microseconds).
// launch_bounds stays (256,4): (256,8) would cap VGPR at 64 and risk the
// round-3 spill catastrophe (VGPR 40 / WRITE_SIZE 330MB / 202us).
// ---------------------------------------------------------------------------
__global__ __launch_bounds__(256, 4) void gemm1_kernel(
    const float* __restrict__ x, const float* __restrict__ evecs,
    float* __restrict__ partial) {
  __shared__ __align__(16) unsigned int ev_t[128 * 32];  // [k][n] bf16, swizzled
  __shared__ __align__(16) unsigned int x_t [32 * 32];   // [c][n] bf16, swizzled

  const int tid   = threadIdx.x;
  const int chunk = blockIdx.x;            // 0..NCHUNK-1
  const int tp    = blockIdx.y;            // 0..7 : kt*4 + ctile
  const int kt    = tp >> 2;
  const int ctile = tp & 3;
  const int w  = tid >> 6;                 // wave 0..3 -> k rows [w*32, w*32+32)
  const int l  = tid & 63;
  const int q  = l >> 4;
  const int lc = l & 15;

  // staging mapping: thread owns 4 consecutive n-rows (r4) x 8 ev-k / 2 x-c (k8)
  const int r4 = tid >> 4;                 // 0..15
  const int k8 = tid & 15;                 // 0..15

  float4v acc[2][2];
#pragma unroll
  for (int a = 0; a < 2; a++)
#pragma unroll
    for (int b = 0; b < 2; b++) acc[a][b] = (float4v)0.0f;

  float4v evr[4][2];
  float2v xr2[4];

  auto load_tile = [&](int it) {
    const int nb = chunk * BN + it * 64 + r4 * 4;
#pragma unroll
    for (int r = 0; r < 4; r++) {
      const int n = nb + r;
      const bool ok = (n < N_NODES);
      const float* evp = evecs + (size_t)n * K_EIG + kt * 128 + k8 * 8;
      const float* xp  = x     + (size_t)n * C_CH  + ctile * 32 + k8 * 2;
      evr[r][0] = ok ? *(const float4v*)(evp)     : (float4v)0.0f;
      evr[r][1] = ok ? *(const float4v*)(evp + 4) : (float4v)0.0f;
      xr2[r]    = ok ? *(const float2v*)(xp)      : (float2v)0.0f;
    }
  };

  load_tile(0);

  for (int ic = 0; ic < NITER; ic++) {
    // stage current registers into LDS, transposed to k-major (b64 writes)
#pragma unroll
    for (int j = 0; j < 8; j++) {
      const int k = k8 * 8 + j;
      const int d = swz(k, r4 * 2);
      uint2v v;
      v.x = pack2(evr[0][j >> 2][j & 3], evr[1][j >> 2][j & 3]);
      v.y = pack2(evr[2][j >> 2][j & 3], evr[3][j >> 2][j & 3]);
      *(uint2v*)&ev_t[d] = v;
    }
#pragma unroll
    for (int j = 0; j < 2; j++) {
      const int c = k8 * 2 + j;
      const int d = swz(c, r4 * 2);
      uint2v v;
      v.x = pack2(xr2[0][j], xr2[1][j]);
      v.y = pack2(xr2[2][j], xr2[3][j]);
      *(uint2v*)&x_t[d] = v;
    }
    __syncthreads();

    // issue next iteration's global loads now; they complete during compute
    if (ic + 1 < NITER) load_tile(ic + 1);

#pragma unroll
    for (int ks = 0; ks < 2; ks++) {
      const int nd0 = ks * 16 + q * 4;     // dword offset of the 8-n slice
      short8 afrag[2];
#pragma unroll
      for (int mt = 0; mt < 2; mt++) {
        const int m = w * 32 + mt * 16 + lc;
        afrag[mt] = *(const short8*)&ev_t[swz(m, nd0)];
      }
#pragma unroll
      for (int ct = 0; ct < 2; ct++) {
        const int c = ct * 16 + lc;
        const short8 b = *(const short8*)&x_t[swz(c, nd0)];
        acc[0][ct] = __builtin_amdgcn_mfma_f32_16x16x32_bf16(afrag[0], b, acc[0][ct], 0, 0, 0);
        acc[1][ct] = __builtin_amdgcn_mfma_f32_16x16x32_bf16(afrag[1], b, acc[1][ct], 0, 0, 0);
      }
    }
    __syncthreads();
  }

  // C/D layout: col = lane&15, row = (lane>>4)*4 + reg
  float* pb = partial + (size_t)(tp * NCHUNK + chunk) * PART_TILE;
#pragma unroll
  for (int mt = 0; mt < 2; mt++)
#pragma unroll
    for (int ct = 0; ct < 2; ct++)
#pragma unroll
      for (int r = 0; r < 4; r++) {
        const int m = w * 32 + mt * 16 + q * 4 + r;
        const int c = ct * 16 + lc;
        pb[m * 32 + c] = acc[mt][ct][r];
      }
}

// ---------------------------------------------------------------------------
// Reduce partials, apply exp(-lambda*t), emit bf16 s pre-shuffled into MFMA
// B-fragment order: idx = (((k/32)*8 + c/16)*64 + ((k%32)/8)*16 + (c%16))*8 + k%8
// Partial layout: partial[(tp*NCHUNK + chunk)*4096 + m*32 + cc],
//   k = (tp>>2)*128 + m, c = (tp&3)*32 + cc
// 1024 blocks (4/CU) x 32 consecutive outputs; 8 chunk-lanes x 4 independent
// accumulators per thread.
// ---------------------------------------------------------------------------
__global__ __launch_bounds__(256) void reduce_kernel(
    const float* __restrict__ partial, const float* __restrict__ evals,
    const float* __restrict__ dt, unsigned short* __restrict__ s_frag) {
  __shared__ float red[256];
  const int t  = threadIdx.x;
  const int o  = blockIdx.x * 32 + (t & 31);   // output index 0..32767
  const int p  = t >> 5;                       // chunk-lane 0..7
  const int tp = o >> 12;                      // 0..7
  const int e  = o & 4095;                     // elem within tile
  const float* base = partial + (size_t)tp * NCHUNK * PART_TILE + e;
  float a0 = 0.f, a1 = 0.f, a2 = 0.f, a3 = 0.f;
  int ch = p;
  for (; ch + 24 < NCHUNK; ch += 32) {
    a0 += base[(size_t)(ch     ) * PART_TILE];
    a1 += base[(size_t)(ch +  8) * PART_TILE];
    a2 += base[(size_t)(ch + 16) * PART_TILE];
    a3 += base[(size_t)(ch + 24) * PART_TILE];
  }
  for (; ch < NCHUNK; ch += 8) a0 += base[(size_t)ch * PART_TILE];
  red[t] = (a0 + a1) + (a2 + a3);
  __syncthreads();
  if (t < 32) {
    float tot = 0.f;
#pragma unroll
    for (int g = 0; g < 8; g++) tot += red[g * 32 + t];
    const int oo = blockIdx.x * 32 + t;
    const int tp2 = oo >> 12;
    const int e2  = oo & 4095;
    const int k = (tp2 >> 2) * 128 + (e2 >> 5);
    const int c = (tp2 & 3) * 32 + (e2 & 31);
    const float tv   = fmaxf(dt[0], 1e-8f);
    const float coef = expf(-evals[k] * tv);
    const float v = tot * coef;
    const int idx = ((((k >> 5) * 8 + (c >> 4)) * 64) + ((k & 31) >> 3) * 16 + (c & 15)) * 8 + (k & 7);
    s_frag[idx] = (unsigned short)bf16_bits(v);
  }
}

// ---------------------------------------------------------------------------
// GEMM2: out[n][c] = sum_k evecs[n][k] * s[k][c]
// No LDS (the r4 64KB LDS copy was ~neutral -- B is L2-resident either way).
// Per ks: all 8 B-fragment loads hoisted (8 L2 loads in flight), A-rows use a
// DEPTH-2 register prefetch (ks+2), so HBM latency (~900cy) is covered by two
// full ks bodies. (256,3): 12 waves/CU; ~140 live VGPR < 170 cap, no spill.
// ---------------------------------------------------------------------------
__global__ __launch_bounds__(256, 3) void gemm2_kernel(
    const float* __restrict__ evecs, const unsigned short* __restrict__ s_frag,
    float* __restrict__ out) {
  const int tid = threadIdx.x;
  const int w  = tid >> 6, l = tid & 63, q = l >> 4, lc = l & 15;
  const int rowbase = blockIdx.x * 128 + w * 32;

  int n0 = rowbase + lc;        n0 = (n0 < N_NODES) ? n0 : (N_NODES - 1);
  int n1 = rowbase + 16 + lc;   n1 = (n1 < N_NODES) ? n1 : (N_NODES - 1);
  const float* row0 = evecs + (size_t)n0 * K_EIG + q * 8;
  const float* row1 = evecs + (size_t)n1 * K_EIG + q * 8;

  float4v acc[2][8];
#pragma unroll
  for (int a = 0; a < 2; a++)
#pragma unroll
    for (int b = 0; b < 8; b++) acc[a][b] = (float4v)0.0f;

  // depth-2 A prefetch: pa[buf][{r0lo, r0hi, r1lo, r1hi}]
  float4v pa[2][4];
  pa[0][0] = *(const float4v*)(row0);
  pa[0][1] = *(const float4v*)(row0 + 4);
  pa[0][2] = *(const float4v*)(row1);
  pa[0][3] = *(const float4v*)(row1 + 4);
  pa[1][0] = *(const float4v*)(row0 + 32);
  pa[1][1] = *(const float4v*)(row0 + 36);
  pa[1][2] = *(const float4v*)(row1 + 32);
  pa[1][3] = *(const float4v*)(row1 + 36);

#pragma unroll
  for (int ks = 0; ks < 8; ks++) {
    const int cur = ks & 1;                // compile-time after full unroll
    // B fragments: 8 hoisted L2 loads in flight
    short8 bfr[8];
#pragma unroll
    for (int ct = 0; ct < 8; ct++)
      bfr[ct] = *(const short8*)&s_frag[(size_t)((ks * 8 + ct) * 64 + l) * 8];
    // a-build VALU overlaps the bfr latency
    short8 a0, a1;
    a0[0] = (short)bf16_bits(pa[cur][0].x); a0[1] = (short)bf16_bits(pa[cur][0].y);
    a0[2] = (short)bf16_bits(pa[cur][0].z); a0[3] = (short)bf16_bits(pa[cur][0].w);
    a0[4] = (short)bf16_bits(pa[cur][1].x); a0[5] = (short)bf16_bits(pa[cur][1].y);
    a0[6] = (short)bf16_bits(pa[cur][1].z); a0[7] = (short)bf16_bits(pa[cur][1].w);
    a1[0] = (short)bf16_bits(pa[cur][2].x); a1[1] = (short)bf16_bits(pa[cur][2].y);
    a1[2] = (short)bf16_bits(pa[cur][2].z); a1[3] = (short)bf16_bits(pa[cur][2].w);
    a1[4] = (short)bf16_bits(pa[cur][3].x); a1[5] = (short)bf16_bits(pa[cur][3].y);
    a1[6] = (short)bf16_bits(pa[cur][3].z); a1[7] = (short)bf16_bits(pa[cur][3].w);
    // refill this buffer with ks+2 (consumed two iterations from now)
    if (ks < 6) {
      pa[cur][0] = *(const float4v*)(row0 + (ks + 2) * 32);
      pa[cur][1] = *(const float4v*)(row0 + (ks + 2) * 32 + 4);
      pa[cur][2] = *(const float4v*)(row1 + (ks + 2) * 32);
      pa[cur][3] = *(const float4v*)(row1 + (ks + 2) * 32 + 4);
    }
#pragma unroll
    for (int ct = 0; ct < 8; ct++) {
      acc[0][ct] = __builtin_amdgcn_mfma_f32_16x16x32_bf16(a0, bfr[ct], acc[0][ct], 0, 0, 0);
      acc[1][ct] = __builtin_amdgcn_mfma_f32_16x16x32_bf16(a1, bfr[ct], acc[1][ct], 0, 0, 0);
    }
  }

#pragma unroll
  for (int rt = 0; rt < 2; rt++)
#pragma unroll
    for (int ct = 0; ct < 8; ct++)
#pragma unroll
      for (int r = 0; r < 4; r++) {
        const int n = rowbase + rt * 16 + q * 4 + r;
        if (n < N_NODES) out[(size_t)n * C_CH + ct * 16 + lc] = acc[rt][ct][r];
      }
}

// ---------------------------------------------------------------------------
extern "C" void kernel_launch(void* const* d_in, const int* in_sizes, int n_in,
                              void* d_out, int out_size, void* d_ws, size_t ws_size,
                              hipStream_t stream) {
  const float* x     = (const float*)d_in[0];   // [N, C]
  const float* evals = (const float*)d_in[1];   // [K]
  const float* evecs = (const float*)d_in[2];   // [N, K]
  const float* dt    = (const float*)d_in[3];   // [1]
  float* out = (float*)d_out;                   // [N, C] fp32

  // d_out doubles as split-K partial scratch: 8*313 tiles * 16KB = 41.0 MB <= 51.2 MB.
  float* partial = out;
  unsigned short* s_frag = (unsigned short*)d_ws;  // 64 KB bf16, fragment-ordered

  dim3 g1(NCHUNK, NTP);
  gemm1_kernel<<<g1, 256, 0, stream>>>(x, evecs, partial);
  reduce_kernel<<<1024, 256, 0, stream>>>(partial, evals, dt, s_frag);
  gemm2_kernel<<<G2_BLOCKS, 256, 0, stream>>>(evecs, s_frag, out);
}

// Round 7
// 250.437 us; speedup vs baseline: 1.0566x; 1.0566x over previous
//
#include <hip/hip_runtime.h>

#define N_NODES 100000
#define K_EIG   256
#define C_CH    128
#define BN      384              // rows per split-K chunk
#define NITER   6                // BN/64
#define NCHUNK  261              // ceil(N_NODES / BN); 261*384 = 100224
#define PART_TILE (128*64)       // floats per partial tile (4*261 tiles * 32KB = 33.4 MB <= d_out)
#define G2_BLOCKS 782            // ceil(N_NODES / 128)

typedef __attribute__((ext_vector_type(8))) short         short8;
typedef __attribute__((ext_vector_type(4))) float         float4v;
typedef __attribute__((ext_vector_type(2))) unsigned int  uint2v;

// fp32 -> bf16 bits with round-to-nearest-even
__device__ __forceinline__ unsigned int bf16_bits(float f) {
  union { float f; unsigned int u; } v; v.f = f;
  unsigned int r = v.u + 0x7fffu + ((v.u >> 16) & 1u);
  return r >> 16;
}
__device__ __forceinline__ unsigned int pack2(float a, float b) {
  return bf16_bits(a) | (bf16_bits(b) << 16);
}

// XOR-swizzled dword index into a k-major LDS tile: row-stride 32 dw (64 bf16).
__device__ __forceinline__ int swz(int row, int nd) {
  return row * 32 + (nd ^ (((row ^ (row >> 3)) & 7) << 2));
}

// ---------------------------------------------------------------------------
// GEMM1: split-K MFMA, EXACT round-4 configuration (measured 72.8-75.0us):
// acc[2][4], 4 ct-tiles of 16 cols (64-col x_t tile). Round-6's failure was
// accidentally keeping round-5's acc[2][2]/ct<2 here -- half of each partial
// tile never written. 4-way tp split is the measured redundancy-vs-occupancy
// optimum (r5's 8-way: FETCH 150->250MB, 91us; r3's (256,6): spill, 202us).
// ---------------------------------------------------------------------------
__global__ __launch_bounds__(256, 4) void gemm1_kernel(
    const float* __restrict__ x, const float* __restrict__ evecs,
    float* __restrict__ partial) {
  __shared__ __align__(16) unsigned int ev_t[128 * 32];  // [k][n] bf16, swizzled
  __shared__ __align__(16) unsigned int x_t [64 * 32];   // [c][n] bf16, swizzled

  const int tid   = threadIdx.x;
  const int chunk = blockIdx.x;            // 0..NCHUNK-1
  const int tp    = blockIdx.y;            // 0..3 : kt*2 + ctile
  const int kt    = tp >> 1;
  const int ctile = tp & 1;
  const int w  = tid >> 6;                 // wave 0..3 -> k rows [w*32, w*32+32)
  const int l  = tid & 63;
  const int q  = l >> 4;
  const int lc = l & 15;

  // staging mapping: thread owns 4 consecutive n-rows (r4) x 8 ev-k / 4 x-c (k8)
  const int r4 = tid >> 4;                 // 0..15
  const int k8 = tid & 15;                 // 0..15

  float4v acc[2][4];
#pragma unroll
  for (int a = 0; a < 2; a++)
#pragma unroll
    for (int b = 0; b < 4; b++) acc[a][b] = (float4v)0.0f;

  float4v evr[4][2], xr[4];

  auto load_tile = [&](int it) {
    const int nb = chunk * BN + it * 64 + r4 * 4;
#pragma unroll
    for (int r = 0; r < 4; r++) {
      const int n = nb + r;
      const bool ok = (n < N_NODES);
      const float* evp = evecs + (size_t)n * K_EIG + kt * 128 + k8 * 8;
      const float* xp  = x     + (size_t)n * C_CH  + ctile * 64 + k8 * 4;
      evr[r][0] = ok ? *(const float4v*)(evp)     : (float4v)0.0f;
      evr[r][1] = ok ? *(const float4v*)(evp + 4) : (float4v)0.0f;
      xr[r]     = ok ? *(const float4v*)(xp)      : (float4v)0.0f;
    }
  };

  load_tile(0);

  for (int ic = 0; ic < NITER; ic++) {
    // stage current registers into LDS, transposed to k-major (b64 writes)
#pragma unroll
    for (int j = 0; j < 8; j++) {
      const int k = k8 * 8 + j;
      const int d = swz(k, r4 * 2);
      uint2v v;
      v.x = pack2(evr[0][j >> 2][j & 3], evr[1][j >> 2][j & 3]);
      v.y = pack2(evr[2][j >> 2][j & 3], evr[3][j >> 2][j & 3]);
      *(uint2v*)&ev_t[d] = v;
    }
#pragma unroll
    for (int j = 0; j < 4; j++) {
      const int c = k8 * 4 + j;
      const int d = swz(c, r4 * 2);
      uint2v v;
      v.x = pack2(xr[0][j], xr[1][j]);
      v.y = pack2(xr[2][j], xr[3][j]);
      *(uint2v*)&x_t[d] = v;
    }
    __syncthreads();

    // issue next iteration's global loads now; they complete during compute
    if (ic + 1 < NITER) load_tile(ic + 1);

#pragma unroll
    for (int ks = 0; ks < 2; ks++) {
      const int nd0 = ks * 16 + q * 4;     // dword offset of the 8-n slice
      short8 afrag[2];
#pragma unroll
      for (int mt = 0; mt < 2; mt++) {
        const int m = w * 32 + mt * 16 + lc;
        afrag[mt] = *(const short8*)&ev_t[swz(m, nd0)];
      }
#pragma unroll
      for (int ct = 0; ct < 4; ct++) {
        const int c = ct * 16 + lc;
        const short8 b = *(const short8*)&x_t[swz(c, nd0)];
        acc[0][ct] = __builtin_amdgcn_mfma_f32_16x16x32_bf16(afrag[0], b, acc[0][ct], 0, 0, 0);
        acc[1][ct] = __builtin_amdgcn_mfma_f32_16x16x32_bf16(afrag[1], b, acc[1][ct], 0, 0, 0);
      }
    }
    __syncthreads();
  }

  // C/D layout: col = lane&15, row = (lane>>4)*4 + reg
  float* pb = partial + (size_t)(tp * NCHUNK + chunk) * PART_TILE;
#pragma unroll
  for (int mt = 0; mt < 2; mt++)
#pragma unroll
    for (int ct = 0; ct < 4; ct++)
#pragma unroll
      for (int r = 0; r < 4; r++) {
        const int m = w * 32 + mt * 16 + q * 4 + r;
        const int c = ct * 16 + lc;
        pb[m * 64 + c] = acc[mt][ct][r];
      }
}

// ---------------------------------------------------------------------------
// Reduce partials, apply exp(-lambda*t), emit bf16 s pre-shuffled into MFMA
// B-fragment order: idx = (((k/32)*8 + c/16)*64 + ((k%32)/8)*16 + (c%16))*8 + k%8
// EXACT round-4 version. LAUNCHED TWICE this round as a differential probe:
// idempotent (reads unchanged partials, writes identical s_frag values via a
// bijective index map), so Delta(total) vs round-4's 243.9us = T_reduce.
// ---------------------------------------------------------------------------
__global__ __launch_bounds__(256) void reduce_kernel(
    const float* __restrict__ partial, const float* __restrict__ evals,
    const float* __restrict__ dt, unsigned short* __restrict__ s_frag) {
  __shared__ float red[256];
  const int t  = threadIdx.x;
  const int o  = blockIdx.x * 32 + (t & 31);   // output index 0..32767
  const int p  = t >> 5;                       // chunk-lane 0..7
  const int tp = o >> 13;                      // 0..3
  const int e  = o & 8191;                     // elem within tile
  const float* base = partial + (size_t)tp * NCHUNK * PART_TILE + e;
  float a0 = 0.f, a1 = 0.f, a2 = 0.f, a3 = 0.f;
  int ch = p;
  for (; ch + 24 < NCHUNK; ch += 32) {
    a0 += base[(size_t)(ch     ) * PART_TILE];
    a1 += base[(size_t)(ch +  8) * PART_TILE];
    a2 += base[(size_t)(ch + 16) * PART_TILE];
    a3 += base[(size_t)(ch + 24) * PART_TILE];
  }
  for (; ch < NCHUNK; ch += 8) a0 += base[(size_t)ch * PART_TILE];
  red[t] = (a0 + a1) + (a2 + a3);
  __syncthreads();
  if (t < 32) {
    float tot = 0.f;
#pragma unroll
    for (int g = 0; g < 8; g++) tot += red[g * 32 + t];
    const int oo = blockIdx.x * 32 + t;
    const int tp2 = oo >> 13;
    const int e2  = oo & 8191;
    const int k = (tp2 >> 1) * 128 + (e2 >> 6);
    const int c = (tp2 & 1) * 64 + (e2 & 63);
    const float tv   = fmaxf(dt[0], 1e-8f);
    const float coef = expf(-evals[k] * tv);
    const float v = tot * coef;
    const int idx = ((((k >> 5) * 8 + (c >> 4)) * 64) + ((k & 31) >> 3) * 16 + (c & 15)) * 8 + (k & 7);
    s_frag[idx] = (unsigned short)bf16_bits(v);
  }
}

// ---------------------------------------------------------------------------
// GEMM2: out[n][c] = sum_k evecs[n][k] * s[k][c]
// Round-5 version (kept): 8 hoisted B-fragment L2 loads in flight per ks,
// depth-2 A register prefetch. (256,3): 12 waves/CU, no spill observed.
// ---------------------------------------------------------------------------
__global__ __launch_bounds__(256, 3) void gemm2_kernel(
    const float* __restrict__ evecs, const unsigned short* __restrict__ s_frag,
    float* __restrict__ out) {
  const int tid = threadIdx.x;
  const int w  = tid >> 6, l = tid & 63, q = l >> 4, lc = l & 15;
  const int rowbase = blockIdx.x * 128 + w * 32;

  int n0 = rowbase + lc;        n0 = (n0 < N_NODES) ? n0 : (N_NODES - 1);
  int n1 = rowbase + 16 + lc;   n1 = (n1 < N_NODES) ? n1 : (N_NODES - 1);
  const float* row0 = evecs + (size_t)n0 * K_EIG + q * 8;
  const float* row1 = evecs + (size_t)n1 * K_EIG + q * 8;

  float4v acc[2][8];
#pragma unroll
  for (int a = 0; a < 2; a++)
#pragma unroll
    for (int b = 0; b < 8; b++) acc[a][b] = (float4v)0.0f;

  // depth-2 A prefetch: pa[buf][{r0lo, r0hi, r1lo, r1hi}]
  float4v pa[2][4];
  pa[0][0] = *(const float4v*)(row0);
  pa[0][1] = *(const float4v*)(row0 + 4);
  pa[0][2] = *(const float4v*)(row1);
  pa[0][3] = *(const float4v*)(row1 + 4);
  pa[1][0] = *(const float4v*)(row0 + 32);
  pa[1][1] = *(const float4v*)(row0 + 36);
  pa[1][2] = *(const float4v*)(row1 + 32);
  pa[1][3] = *(const float4v*)(row1 + 36);

#pragma unroll
  for (int ks = 0; ks < 8; ks++) {
    const int cur = ks & 1;                // compile-time after full unroll
    // B fragments: 8 hoisted L2 loads in flight
    short8 bfr[8];
#pragma unroll
    for (int ct = 0; ct < 8; ct++)
      bfr[ct] = *(const short8*)&s_frag[(size_t)((ks * 8 + ct) * 64 + l) * 8];
    // a-build VALU overlaps the bfr latency
    short8 a0, a1;
    a0[0] = (short)bf16_bits(pa[cur][0].x); a0[1] = (short)bf16_bits(pa[cur][0].y);
    a0[2] = (short)bf16_bits(pa[cur][0].z); a0[3] = (short)bf16_bits(pa[cur][0].w);
    a0[4] = (short)bf16_bits(pa[cur][1].x); a0[5] = (short)bf16_bits(pa[cur][1].y);
    a0[6] = (short)bf16_bits(pa[cur][1].z); a0[7] = (short)bf16_bits(pa[cur][1].w);
    a1[0] = (short)bf16_bits(pa[cur][2].x); a1[1] = (short)bf16_bits(pa[cur][2].y);
    a1[2] = (short)bf16_bits(pa[cur][2].z); a1[3] = (short)bf16_bits(pa[cur][2].w);
    a1[4] = (short)bf16_bits(pa[cur][3].x); a1[5] = (short)bf16_bits(pa[cur][3].y);
    a1[6] = (short)bf16_bits(pa[cur][3].z); a1[7] = (short)bf16_bits(pa[cur][3].w);
    // refill this buffer with ks+2 (consumed two iterations from now)
    if (ks < 6) {
      pa[cur][0] = *(const float4v*)(row0 + (ks + 2) * 32);
      pa[cur][1] = *(const float4v*)(row0 + (ks + 2) * 32 + 4);
      pa[cur][2] = *(const float4v*)(row1 + (ks + 2) * 32);
      pa[cur][3] = *(const float4v*)(row1 + (ks + 2) * 32 + 4);
    }
#pragma unroll
    for (int ct = 0; ct < 8; ct++) {
      acc[0][ct] = __builtin_amdgcn_mfma_f32_16x16x32_bf16(a0, bfr[ct], acc[0][ct], 0, 0, 0);
      acc[1][ct] = __builtin_amdgcn_mfma_f32_16x16x32_bf16(a1, bfr[ct], acc[1][ct], 0, 0, 0);
    }
  }

#pragma unroll
  for (int rt = 0; rt < 2; rt++)
#pragma unroll
    for (int ct = 0; ct < 8; ct++)
#pragma unroll
      for (int r = 0; r < 4; r++) {
        const int n = rowbase + rt * 16 + q * 4 + r;
        if (n < N_NODES) out[(size_t)n * C_CH + ct * 16 + lc] = acc[rt][ct][r];
      }
}

// ---------------------------------------------------------------------------
extern "C" void kernel_launch(void* const* d_in, const int* in_sizes, int n_in,
                              void* d_out, int out_size, void* d_ws, size_t ws_size,
                              hipStream_t stream) {
  const float* x     = (const float*)d_in[0];   // [N, C]
  const float* evals = (const float*)d_in[1];   // [K]
  const float* evecs = (const float*)d_in[2];   // [N, K]
  const float* dt    = (const float*)d_in[3];   // [1]
  float* out = (float*)d_out;                   // [N, C] fp32

  // d_out doubles as split-K partial scratch: 4*261 tiles * 32KB = 33.4 MB <= 51.2 MB.
  float* partial = out;
  unsigned short* s_frag = (unsigned short*)d_ws;  // 64 KB bf16, fragment-ordered

  dim3 g1(NCHUNK, 4);
  gemm1_kernel<<<g1, 256, 0, stream>>>(x, evecs, partial);
  // DIFFERENTIAL PROBE: reduce launched twice (idempotent -- identical
  // output). Delta(total) vs round-4's 243.9us = T_reduce + ~2us launch.
  reduce_kernel<<<1024, 256, 0, stream>>>(partial, evals, dt, s_frag);
  reduce_kernel<<<1024, 256, 0, stream>>>(partial, evals, dt, s_frag);
  gemm2_kernel<<<G2_BLOCKS, 256, 0, stream>>>(evecs, s_frag, out);
}

// Round 8
// 245.622 us; speedup vs baseline: 1.0774x; 1.0196x over previous
//
#include <hip/hip_runtime.h>

#define N_NODES 100000
#define K_EIG   256
#define C_CH    128
#define BN      448              // rows per split-K chunk (grid 224*4=896 <= 1024 -> ONE dispatch round)
#define NITER   7                // BN/64
#define NCHUNK  224              // ceil(N_NODES / BN); 224*448 = 100352
#define PART_TILE (128*64)       // floats per partial tile (4*224 tiles * 32KB = 28.7 MB <= d_out)
#define G2_BLOCKS 1563           // ceil(N_NODES / 64)

typedef __attribute__((ext_vector_type(8))) short         short8;
typedef __attribute__((ext_vector_type(4))) float         float4v;
typedef __attribute__((ext_vector_type(2))) unsigned int  uint2v;

// fp32 -> bf16 bits with round-to-nearest-even
__device__ __forceinline__ unsigned int bf16_bits(float f) {
  union { float f; unsigned int u; } v; v.f = f;
  unsigned int r = v.u + 0x7fffu + ((v.u >> 16) & 1u);
  return r >> 16;
}
__device__ __forceinline__ unsigned int pack2(float a, float b) {
  return bf16_bits(a) | (bf16_bits(b) << 16);
}

// XOR-swizzled dword index into a k-major LDS tile: row-stride 32 dw (64 bf16).
__device__ __forceinline__ int swz(int row, int nd) {
  return row * 32 + (nd ^ (((row ^ (row >> 3)) & 7) << 2));
}

// ---------------------------------------------------------------------------
// GEMM1: split-K MFMA, r4-proven body (72.8-75us), ONLY BN changed 384->448.
// r7 diagnosis: grid 1044 > single-round capacity 1024 -> the 20-block tail
// round stretched the kernel to ~1.6x T_block (predicted avg occ 2.53
// blocks/CU under this model; measured 2.56). Grid 896 -> one round, no tail.
// Known cliffs (do not touch): launch_bounds(256,6) spills (r3: VGPR 40,
// WRITE 330MB, 202us); 8-way tp split breaks L3 dup absorption (r5: FETCH
// 150->250MB, 91us); acc must be [2][4]/ct<4 (r6 correctness).
// ---------------------------------------------------------------------------
__global__ __launch_bounds__(256, 4) void gemm1_kernel(
    const float* __restrict__ x, const float* __restrict__ evecs,
    float* __restrict__ partial) {
  __shared__ __align__(16) unsigned int ev_t[128 * 32];  // [k][n] bf16, swizzled
  __shared__ __align__(16) unsigned int x_t [64 * 32];   // [c][n] bf16, swizzled

  const int tid   = threadIdx.x;
  const int chunk = blockIdx.x;            // 0..NCHUNK-1
  const int tp    = blockIdx.y;            // 0..3 : kt*2 + ctile
  const int kt    = tp >> 1;
  const int ctile = tp & 1;
  const int w  = tid >> 6;                 // wave 0..3 -> k rows [w*32, w*32+32)
  const int l  = tid & 63;
  const int q  = l >> 4;
  const int lc = l & 15;

  // staging mapping: thread owns 4 consecutive n-rows (r4) x 8 ev-k / 4 x-c (k8)
  const int r4 = tid >> 4;                 // 0..15
  const int k8 = tid & 15;                 // 0..15

  float4v acc[2][4];
#pragma unroll
  for (int a = 0; a < 2; a++)
#pragma unroll
    for (int b = 0; b < 4; b++) acc[a][b] = (float4v)0.0f;

  float4v evr[4][2], xr[4];

  auto load_tile = [&](int it) {
    const int nb = chunk * BN + it * 64 + r4 * 4;
#pragma unroll
    for (int r = 0; r < 4; r++) {
      const int n = nb + r;
      const bool ok = (n < N_NODES);
      const float* evp = evecs + (size_t)n * K_EIG + kt * 128 + k8 * 8;
      const float* xp  = x     + (size_t)n * C_CH  + ctile * 64 + k8 * 4;
      evr[r][0] = ok ? *(const float4v*)(evp)     : (float4v)0.0f;
      evr[r][1] = ok ? *(const float4v*)(evp + 4) : (float4v)0.0f;
      xr[r]     = ok ? *(const float4v*)(xp)      : (float4v)0.0f;
    }
  };

  load_tile(0);

  for (int ic = 0; ic < NITER; ic++) {
    // stage current registers into LDS, transposed to k-major (b64 writes)
#pragma unroll
    for (int j = 0; j < 8; j++) {
      const int k = k8 * 8 + j;
      const int d = swz(k, r4 * 2);
      uint2v v;
      v.x = pack2(evr[0][j >> 2][j & 3], evr[1][j >> 2][j & 3]);
      v.y = pack2(evr[2][j >> 2][j & 3], evr[3][j >> 2][j & 3]);
      *(uint2v*)&ev_t[d] = v;
    }
#pragma unroll
    for (int j = 0; j < 4; j++) {
      const int c = k8 * 4 + j;
      const int d = swz(c, r4 * 2);
      uint2v v;
      v.x = pack2(xr[0][j], xr[1][j]);
      v.y = pack2(xr[2][j], xr[3][j]);
      *(uint2v*)&x_t[d] = v;
    }
    __syncthreads();

    // issue next iteration's global loads now; they complete during compute
    if (ic + 1 < NITER) load_tile(ic + 1);

#pragma unroll
    for (int ks = 0; ks < 2; ks++) {
      const int nd0 = ks * 16 + q * 4;     // dword offset of the 8-n slice
      short8 afrag[2];
#pragma unroll
      for (int mt = 0; mt < 2; mt++) {
        const int m = w * 32 + mt * 16 + lc;
        afrag[mt] = *(const short8*)&ev_t[swz(m, nd0)];
      }
#pragma unroll
      for (int ct = 0; ct < 4; ct++) {
        const int c = ct * 16 + lc;
        const short8 b = *(const short8*)&x_t[swz(c, nd0)];
        acc[0][ct] = __builtin_amdgcn_mfma_f32_16x16x32_bf16(afrag[0], b, acc[0][ct], 0, 0, 0);
        acc[1][ct] = __builtin_amdgcn_mfma_f32_16x16x32_bf16(afrag[1], b, acc[1][ct], 0, 0, 0);
      }
    }
    __syncthreads();
  }

  // C/D layout: col = lane&15, row = (lane>>4)*4 + reg
  float* pb = partial + (size_t)(tp * NCHUNK + chunk) * PART_TILE;
#pragma unroll
  for (int mt = 0; mt < 2; mt++)
#pragma unroll
    for (int ct = 0; ct < 4; ct++)
#pragma unroll
      for (int r = 0; r < 4; r++) {
        const int m = w * 32 + mt * 16 + q * 4 + r;
        const int c = ct * 16 + lc;
        pb[m * 64 + c] = acc[mt][ct][r];
      }
}

// ---------------------------------------------------------------------------
// Reduce partials, apply exp(-lambda*t), emit bf16 s pre-shuffled into MFMA
// B-fragment order: idx = (((k/32)*8 + c/16)*64 + ((k%32)/8)*16 + (c%16))*8 + k%8
// r4-exact version; measured ~6.5us total impact (r7 double-launch probe).
// NCHUNK=224: main loop runs exactly 7 steps per lane, no remainder.
// ---------------------------------------------------------------------------
__global__ __launch_bounds__(256) void reduce_kernel(
    const float* __restrict__ partial, const float* __restrict__ evals,
    const float* __restrict__ dt, unsigned short* __restrict__ s_frag) {
  __shared__ float red[256];
  const int t  = threadIdx.x;
  const int o  = blockIdx.x * 32 + (t & 31);   // output index 0..32767
  const int p  = t >> 5;                       // chunk-lane 0..7
  const int tp = o >> 13;                      // 0..3
  const int e  = o & 8191;                     // elem within tile
  const float* base = partial + (size_t)tp * NCHUNK * PART_TILE + e;
  float a0 = 0.f, a1 = 0.f, a2 = 0.f, a3 = 0.f;
  int ch = p;
  for (; ch + 24 < NCHUNK; ch += 32) {
    a0 += base[(size_t)(ch     ) * PART_TILE];
    a1 += base[(size_t)(ch +  8) * PART_TILE];
    a2 += base[(size_t)(ch + 16) * PART_TILE];
    a3 += base[(size_t)(ch + 24) * PART_TILE];
  }
  for (; ch < NCHUNK; ch += 8) a0 += base[(size_t)ch * PART_TILE];
  red[t] = (a0 + a1) + (a2 + a3);
  __syncthreads();
  if (t < 32) {
    float tot = 0.f;
#pragma unroll
    for (int g = 0; g < 8; g++) tot += red[g * 32 + t];
    const int oo = blockIdx.x * 32 + t;
    const int tp2 = oo >> 13;
    const int e2  = oo & 8191;
    const int k = (tp2 >> 1) * 128 + (e2 >> 6);
    const int c = (tp2 & 1) * 64 + (e2 & 63);
    const float tv   = fmaxf(dt[0], 1e-8f);
    const float coef = expf(-evals[k] * tv);
    const float v = tot * coef;
    const int idx = ((((k >> 5) * 8 + (c >> 4)) * 64) + ((k & 31) >> 3) * 16 + (c & 15)) * 8 + (k & 7);
    s_frag[idx] = (unsigned short)bf16_bits(v);
  }
}

// ---------------------------------------------------------------------------
// GEMM2: out[n][c] = sum_k evecs[n][k] * s[k][c]
// Tail fix: old config was 782 blocks at 3-block/CU capacity (768) -> 14-block
// tail round ~doubled the kernel. New: ONE 16-row tile per wave (64 rows per
// 256-thread block, grid 1563), live set ~100 VGPR (acc 32 + bfr 32 + A
// prefetch 16 + misc) < 128 cliff -> 4 blocks/CU at launch_bounds(256,4).
// Keeps the 8-wide hoisted B-fragment L2 MLP and depth-1 A register prefetch.
// A-frag/C-write index math identical to the proven 2-tile version (rt=0).
// ---------------------------------------------------------------------------
__global__ __launch_bounds__(256, 4) void gemm2_kernel(
    const float* __restrict__ evecs, const unsigned short* __restrict__ s_frag,
    float* __restrict__ out) {
  const int tid = threadIdx.x;
  const int w  = tid >> 6, l = tid & 63, q = l >> 4, lc = l & 15;
  const int rowbase = blockIdx.x * 64 + w * 16;

  int n0 = rowbase + lc;        n0 = (n0 < N_NODES) ? n0 : (N_NODES - 1);
  const float* row0 = evecs + (size_t)n0 * K_EIG + q * 8;

  float4v acc[8];
#pragma unroll
  for (int b = 0; b < 8; b++) acc[b] = (float4v)0.0f;

  float4v c00 = *(const float4v*)(row0);
  float4v c01 = *(const float4v*)(row0 + 4);

#pragma unroll
  for (int ks = 0; ks < 8; ks++) {
    // B fragments: 8 hoisted L2 loads in flight
    short8 bfr[8];
#pragma unroll
    for (int ct = 0; ct < 8; ct++)
      bfr[ct] = *(const short8*)&s_frag[(size_t)((ks * 8 + ct) * 64 + l) * 8];
    // next-ks A loads in flight; a-build VALU covers the bfr latency
    float4v nx00, nx01;
    if (ks < 7) {
      nx00 = *(const float4v*)(row0 + (ks + 1) * 32);
      nx01 = *(const float4v*)(row0 + (ks + 1) * 32 + 4);
    }
    short8 a0;
    a0[0] = (short)bf16_bits(c00.x); a0[1] = (short)bf16_bits(c00.y);
    a0[2] = (short)bf16_bits(c00.z); a0[3] = (short)bf16_bits(c00.w);
    a0[4] = (short)bf16_bits(c01.x); a0[5] = (short)bf16_bits(c01.y);
    a0[6] = (short)bf16_bits(c01.z); a0[7] = (short)bf16_bits(c01.w);
#pragma unroll
    for (int ct = 0; ct < 8; ct++)
      acc[ct] = __builtin_amdgcn_mfma_f32_16x16x32_bf16(a0, bfr[ct], acc[ct], 0, 0, 0);
    c00 = nx00; c01 = nx01;
  }

#pragma unroll
  for (int ct = 0; ct < 8; ct++)
#pragma unroll
    for (int r = 0; r < 4; r++) {
      const int n = rowbase + q * 4 + r;
      if (n < N_NODES) out[(size_t)n * C_CH + ct * 16 + lc] = acc[ct][r];
    }
}

// ---------------------------------------------------------------------------
extern "C" void kernel_launch(void* const* d_in, const int* in_sizes, int n_in,
                              void* d_out, int out_size, void* d_ws, size_t ws_size,
                              hipStream_t stream) {
  const float* x     = (const float*)d_in[0];   // [N, C]
  const float* evals = (const float*)d_in[1];   // [K]
  const float* evecs = (const float*)d_in[2];   // [N, K]
  const float* dt    = (const float*)d_in[3];   // [1]
  float* out = (float*)d_out;                   // [N, C] fp32

  // d_out doubles as split-K partial scratch: 4*224 tiles * 32KB = 28.7 MB <= 51.2 MB.
  float* partial = out;
  unsigned short* s_frag = (unsigned short*)d_ws;  // 64 KB bf16, fragment-ordered

  dim3 g1(NCHUNK, 4);
  gemm1_kernel<<<g1, 256, 0, stream>>>(x, evecs, partial);
  reduce_kernel<<<1024, 256, 0, stream>>>(partial, evals, dt, s_frag);
  gemm2_kernel<<<G2_BLOCKS, 256, 0, stream>>>(evecs, s_frag, out);
}